// Round 5
// baseline (61.397 us; speedup 1.0000x reference)
//
#include <hip/hip_runtime.h>

// Problem constants
#define NT 64
#define NF 1024
#define NB 1024      // batch (GEMM M)
#define ND 2048      // d width (GEMM K)
#define NN 1344      // GEMM N = 64 trees * 21 cols
#define NP 27
#define NW2ROW 1027
#define BK 64        // GEMM K-tile
#define NCONV 1024   // convert blocks: NB*ND/(256*8)

typedef __attribute__((ext_vector_type(8))) short short8;
typedef __attribute__((ext_vector_type(4))) float f32x4;

static __device__ __forceinline__ unsigned short f2bf(float x) {
    unsigned u = __float_as_uint(x);
    unsigned r = (u + 0x7FFFu + ((u >> 16) & 1u)) >> 16;   // RNE
    return (unsigned short)r;
}

// ---------------------------------------------------------------------------
// prep: blocks [0, NN) build folded weights Wf[n][j] (bf16) via LDS
// accumulation; blocks [NN, NN+NCONV) convert d -> bf16. Block 0 also zeroes
// the epilogue ticket counters (graph stream order makes this safe).
// ---------------------------------------------------------------------------
__global__ __launch_bounds__(256) void prep_kernel(
    const int* __restrict__ idx, const float* __restrict__ w_clc,
    const float* __restrict__ w1, const float* __restrict__ w2,
    const float* __restrict__ d, unsigned short* __restrict__ Wf,
    unsigned short* __restrict__ db, int* __restrict__ counters)
{
    __shared__ float tile[ND];   // 8 KB
    int bid = blockIdx.x;
    int tid = threadIdx.x;

    if (bid == 0 && tid < 8) counters[tid] = 0;

    if (bid < NN) {
        // ---- scatter: one (t, k) column of the folded weights ----
        int t = bid / 21, k = bid % 21;

        for (int i = tid; i < ND; i += 256) tile[i] = 0.f;
        __syncthreads();

        const float* src; int stride;
        if (k < 2)      { src = w_clc + (size_t)t * 2048 + k;            stride = 2;  }
        else if (k < 5) { src = w1    + (size_t)t * 3072 + (k - 2);      stride = 3;  }
        else            { src = w2    + (size_t)t * NW2ROW * 16 + (k-5); stride = 16; }

        const int* idt = idx + t * NF;
        for (int f = tid; f < NF; f += 256)
            atomicAdd(&tile[idt[f]], src[(size_t)f * stride]);
        __syncthreads();

        int i8 = tid * 8;
        union { unsigned short u[8]; uint4 v; } pk;
#pragma unroll
        for (int e = 0; e < 8; ++e) pk.u[e] = f2bf(tile[i8 + e]);
        *(uint4*)&Wf[(size_t)bid * ND + i8] = pk.v;
    } else {
        // ---- convert: 8 f32 -> 8 bf16 per thread ----
        int cb = bid - NN;
        int i8 = (cb * 256 + tid) * 8;
        float4 a = *(const float4*)&d[i8];
        float4 b = *(const float4*)&d[i8 + 4];
        union { unsigned short u[8]; uint4 v; } pk;
        pk.u[0] = f2bf(a.x); pk.u[1] = f2bf(a.y); pk.u[2] = f2bf(a.z); pk.u[3] = f2bf(a.w);
        pk.u[4] = f2bf(b.x); pk.u[5] = f2bf(b.y); pk.u[6] = f2bf(b.z); pk.u[7] = f2bf(b.w);
        *(uint4*)&db[i8] = pk.v;
    }
}

// ---------------------------------------------------------------------------
// GEMM: Ct[kh][n][b] = sum_{j in half kh} db[b][j] * Wf[n][j]  (bf16 MFMA)
// 64x64 tile, BK=64, 4 waves (2x2), 2x2 16x16x32 fragments per wave,
// global_load_lds(16B) staging, double-buffered LDS, split-K=2.
// Grid (16, 21, 2), block 256.
// ---------------------------------------------------------------------------
__global__ __launch_bounds__(256) void gemm_kernel(
    const unsigned short* __restrict__ A,   // db [1024][2048]
    const unsigned short* __restrict__ Bm,  // Wf [1344][2048]
    float* __restrict__ Ct)                 // [2][1344][1024]
{
    __shared__ __align__(16) unsigned short As[2][64][BK];  // 8 KB each
    __shared__ __align__(16) unsigned short Bs[2][64][BK];

    int tid = threadIdx.x;
    int lane = tid & 63;
    int wv = tid >> 6;          // 0..3
    int wr = wv >> 1, wc = wv & 1;
    int m0 = blockIdx.x * 64;
    int n0 = blockIdx.y * 64;
    int kh = blockIdx.z;
    size_t kbase = (size_t)kh * 1024;   // element offset into K

    f32x4 acc[2][2];
#pragma unroll
    for (int mi = 0; mi < 2; ++mi)
#pragma unroll
        for (int ni = 0; ni < 2; ++ni) acc[mi][ni] = (f32x4)0.f;

    int r0 = lane & 15;          // fragment row/col within 16
    int kq = lane >> 4;          // 0..3 -> k-subgroup of 8

#define STAGE(buf, kt)                                                          \
    {                                                                           \
        size_t koff = kbase + (size_t)(kt) * BK;                                \
        _Pragma("unroll")                                                       \
        for (int p = 0; p < 2; ++p) {                                           \
            int chunk = p * 256 + wv * 64 + lane;                               \
            int row = chunk >> 3, c = chunk & 7;                                \
            const unsigned short* ga = A + (size_t)(m0 + row) * ND + koff + c*8;\
            __builtin_amdgcn_global_load_lds(                                   \
                (const __attribute__((address_space(1))) void*)ga,              \
                (__attribute__((address_space(3))) void*)&As[buf][row][c * 8],  \
                16, 0, 0);                                                      \
            const unsigned short* gb = Bm + (size_t)(n0 + row) * ND + koff + c*8;\
            __builtin_amdgcn_global_load_lds(                                   \
                (const __attribute__((address_space(1))) void*)gb,              \
                (__attribute__((address_space(3))) void*)&Bs[buf][row][c * 8],  \
                16, 0, 0);                                                      \
        }                                                                       \
    }

    STAGE(0, 0);
    __syncthreads();

    int cur = 0;
    for (int kt = 0; kt < 16; ++kt) {
        if (kt < 15) STAGE(cur ^ 1, kt + 1);

        short8 af[2][2], bf[2][2];   // [rep][ksub]
#pragma unroll
        for (int mi = 0; mi < 2; ++mi)
#pragma unroll
            for (int ks = 0; ks < 2; ++ks) {
                af[mi][ks] = *(const short8*)&As[cur][wr*32 + mi*16 + r0][ks*32 + kq*8];
                bf[mi][ks] = *(const short8*)&Bs[cur][wc*32 + mi*16 + r0][ks*32 + kq*8];
            }
#pragma unroll
        for (int ks = 0; ks < 2; ++ks)
#pragma unroll
            for (int mi = 0; mi < 2; ++mi)
#pragma unroll
                for (int ni = 0; ni < 2; ++ni)
                    acc[mi][ni] = __builtin_amdgcn_mfma_f32_16x16x32_bf16(
                        af[mi][ks], bf[ni][ks], acc[mi][ni], 0, 0, 0);
        __syncthreads();
        cur ^= 1;
    }

    // C/D layout (verified m89/m91): row=(lane>>4)*4+reg, col=lane&15.
#pragma unroll
    for (int mi = 0; mi < 2; ++mi)
#pragma unroll
        for (int ni = 0; ni < 2; ++ni) {
            int n = n0 + wc * 32 + ni * 16 + r0;
            int b = m0 + wr * 32 + mi * 16 + kq * 4;
            *(f32x4*)&Ct[((size_t)kh * NN + n) * NB + b] = acc[mi][ni];
        }
#undef STAGE
}

// ---------------------------------------------------------------------------
// Fused epilogue + finalize. Grid (4 b-groups, 16 tG), block 256.
// Phase 1 (all 64 blocks): per (b, t) softmax/gate math for 4 trees,
// pre-reduced s[27] -> ptl2[tG][27][b].
// Phase 2 (last block per b-group via device-scope ticket): reduce the 16
// tG slices for its 256 b's, normalize, write out.
// ---------------------------------------------------------------------------
__global__ __launch_bounds__(256) void epilogue_kernel(
    const float* __restrict__ Ct, const float* __restrict__ b_clc,
    const float* __restrict__ b1, const float* __restrict__ b2,
    const float* __restrict__ w2, const int* __restrict__ cc,
    float* __restrict__ ptl2, int* __restrict__ counters,
    float* __restrict__ out)
{
    int tid = threadIdx.x;
    int bg = blockIdx.x;        // 0..3
    int tG = blockIdx.y;        // 0..15
    int b = bg * 256 + tid;

    float s[NP];
#pragma unroll
    for (int k = 0; k < NP; ++k) s[k] = 0.f;

    for (int ti = 0; ti < 4; ++ti) {
        int t = tG * 4 + ti;
        float acc[21];
#pragma unroll
        for (int k = 0; k < 21; ++k) {
            size_t n = (size_t)t * 21 + k;
            acc[k] = Ct[n * NB + b] + Ct[((size_t)NN + n) * NB + b];
        }

        float L0 = acc[0] + b_clc[t * 2 + 0];
        float L1 = acc[1] + b_clc[t * 2 + 1];
        float mm = fmaxf(L0, L1);
        float e0 = __expf(L0 - mm), e1 = __expf(L1 - mm);
        float gate = e1 / (e0 + e1);

        float l1v[3];
        float m1 = -3.0e38f;
#pragma unroll
        for (int c = 0; c < 3; ++c) {
            l1v[c] = acc[2 + c] + b1[t * 3 + c];
            m1 = fmaxf(m1, l1v[c]);
        }
        float p1[3]; float S1 = 0.f;
#pragma unroll
        for (int c = 0; c < 3; ++c) { p1[c] = __expf(l1v[c] - m1); S1 += p1[c]; }
        float invS1g = gate / S1;

        float r0 = fmaxf(l1v[0], 0.f);
        float r1 = fmaxf(l1v[1], 0.f);
        float r2 = fmaxf(l1v[2], 0.f);

        const float* w2t = w2 + ((size_t)t * NW2ROW + NF) * 16;
        float l2[16]; float m2 = -3.0e38f;
#pragma unroll
        for (int nn = 0; nn < 16; ++nn) {
            float v = acc[5 + nn] + b2[t * 16 + nn];
            v = fmaf(r0, w2t[nn], v);
            v = fmaf(r1, w2t[16 + nn], v);
            v = fmaf(r2, w2t[32 + nn], v);
            l2[nn] = v;
            m2 = fmaxf(m2, v);
        }
        float S2 = 0.f; float p2[16];
#pragma unroll
        for (int nn = 0; nn < 16; ++nn) { p2[nn] = __expf(l2[nn] - m2); S2 += p2[nn]; }
        float invS2g = gate * __frcp_rn(S2);

#pragma unroll
        for (int c = 0; c < 3; ++c) {
            int sl = cc[t * 3 + c];
            float pc = p1[c] * invS1g;
#pragma unroll
            for (int x = 0; x < 5; ++x) {
                if (sl == x) { s[x] += pc; s[5 + x] += gate; }
            }
        }
#pragma unroll
        for (int nn = 0; nn < 16; ++nn) s[10 + nn] += p2[nn] * invS2g;
        s[26] += gate;
    }

    float* pt = ptl2 + (size_t)tG * NP * NB + b;
#pragma unroll
    for (int k = 0; k < NP; ++k) pt[(size_t)k * NB] = s[k];

    // ---- last-block ticket (rocPRIM pattern) ----
    __threadfence();
    __shared__ int ticket;
    if (tid == 0) ticket = atomicAdd(&counters[bg], 1);
    __syncthreads();
    if (ticket != 15) return;
    __threadfence();

    // ---- finalize this b-group ----
    float f[NP];
#pragma unroll
    for (int k = 0; k < NP; ++k) f[k] = 0.f;
    for (int g = 0; g < 16; ++g) {
        const float* pg = ptl2 + (size_t)g * NP * NB + b;
#pragma unroll
        for (int k = 0; k < NP; ++k) f[k] += pg[(size_t)k * NB];
    }

    float* ob = out + (size_t)b * 21;
#pragma unroll
    for (int x = 0; x < 5; ++x) {
        float c = f[5 + x];
        ob[x] = (c > 0.f) ? (f[x] / c) : 0.f;
    }
    float invg = 1.f / f[26];
#pragma unroll
    for (int n = 0; n < 16; ++n) ob[5 + n] = f[10 + n] * invg;
}

// ---------------------------------------------------------------------------
extern "C" void kernel_launch(void* const* d_in, const int* in_sizes, int n_in,
                              void* d_out, int out_size, void* d_ws, size_t ws_size,
                              hipStream_t stream)
{
    const float* d     = (const float*)d_in[0];
    const int*   idx   = (const int*)  d_in[1];
    const int*   cc    = (const int*)  d_in[2];
    const float* w_clc = (const float*)d_in[3];
    const float* b_clc = (const float*)d_in[4];
    const float* w1    = (const float*)d_in[5];
    const float* b1    = (const float*)d_in[6];
    const float* w2    = (const float*)d_in[7];
    const float* b2    = (const float*)d_in[8];
    float* out = (float*)d_out;

    // ws layout
    unsigned short* Wf = (unsigned short*)d_ws;            // [1344][2048] bf16
    unsigned short* db = Wf + (size_t)NN * ND;             // [1024][2048] bf16
    float* Ct   = (float*)(db + (size_t)NB * ND);          // [2][1344][1024] f32
    float* ptl2 = Ct + (size_t)2 * NN * NB;                // [16][27][1024] f32
    int* counters = (int*)(ptl2 + (size_t)16 * NP * NB);   // [8]

    prep_kernel<<<NN + NCONV, 256, 0, stream>>>(idx, w_clc, w1, w2, d, Wf, db, counters);
    gemm_kernel<<<dim3(NB / 64, NN / 64, 2), 256, 0, stream>>>(db, Wf, Ct);
    epilogue_kernel<<<dim3(4, 16), 256, 0, stream>>>(Ct, b_clc, b1, b2, w2, cc, ptl2, counters, out);
}

// Round 6
// 50.289 us; speedup vs baseline: 1.2209x; 1.2209x over previous
//
#include <hip/hip_runtime.h>

// Problem constants
#define NT 64        // trees
#define NF 1024      // features per tree
#define NB 1024      // batch (GEMM M)
#define ND 2048      // d width (GEMM K)
#define NTP 32       // padded columns per tree
#define NN2 (NT * NTP)   // 2048 = padded GEMM N
#define NP 27        // partials per (b, tree-pair)
#define NW2ROW 1027
#define BK 64        // GEMM K-tile
#define NSCAT 2048   // scatter blocks (64 t x 32 k)
#define NCONV 1024   // convert blocks

typedef __attribute__((ext_vector_type(8))) short short8;
typedef __attribute__((ext_vector_type(4))) float f32x4;

static __device__ __forceinline__ unsigned short f2bf(float x) {
    unsigned u = __float_as_uint(x);
    unsigned r = (u + 0x7FFFu + ((u >> 16) & 1u)) >> 16;   // RNE
    return (unsigned short)r;
}

// ---------------------------------------------------------------------------
// prep: blocks [0, NSCAT) build padded folded weights Wf[n][j] (bf16),
// n = t*32 + k (k in [21,32) rows are zeroed); blocks [NSCAT, NSCAT+NCONV)
// convert d -> bf16.
// ---------------------------------------------------------------------------
__global__ __launch_bounds__(256) void prep_kernel(
    const int* __restrict__ idx, const float* __restrict__ w_clc,
    const float* __restrict__ w1, const float* __restrict__ w2,
    const float* __restrict__ d, unsigned short* __restrict__ Wf,
    unsigned short* __restrict__ db)
{
    __shared__ float tile[ND];   // 8 KB
    int bid = blockIdx.x;
    int tid = threadIdx.x;

    if (bid < NSCAT) {
        int t = bid >> 5, k = bid & 31;   // row n == bid
        if (k >= 21) {                     // pad row: zeros
            uint4 z = make_uint4(0, 0, 0, 0);
            *(uint4*)&Wf[(size_t)bid * ND + tid * 8] = z;
            return;
        }
        for (int i = tid; i < ND; i += 256) tile[i] = 0.f;
        __syncthreads();

        const float* src; int stride;
        if (k < 2)      { src = w_clc + (size_t)t * 2048 + k;            stride = 2;  }
        else if (k < 5) { src = w1    + (size_t)t * 3072 + (k - 2);      stride = 3;  }
        else            { src = w2    + (size_t)t * NW2ROW * 16 + (k-5); stride = 16; }

        const int* idt = idx + t * NF;
        for (int f = tid; f < NF; f += 256)
            atomicAdd(&tile[idt[f]], src[(size_t)f * stride]);
        __syncthreads();

        int i8 = tid * 8;
        union { unsigned short u[8]; uint4 v; } pk;
#pragma unroll
        for (int e = 0; e < 8; ++e) pk.u[e] = f2bf(tile[i8 + e]);
        *(uint4*)&Wf[(size_t)bid * ND + i8] = pk.v;
    } else {
        int cb = bid - NSCAT;
        int i8 = (cb * 256 + tid) * 8;
        float4 a = *(const float4*)&d[i8];
        float4 b = *(const float4*)&d[i8 + 4];
        union { unsigned short u[8]; uint4 v; } pk;
        pk.u[0] = f2bf(a.x); pk.u[1] = f2bf(a.y); pk.u[2] = f2bf(a.z); pk.u[3] = f2bf(a.w);
        pk.u[4] = f2bf(b.x); pk.u[5] = f2bf(b.y); pk.u[6] = f2bf(b.z); pk.u[7] = f2bf(b.w);
        *(uint4*)&db[i8] = pk.v;
    }
}

// ---------------------------------------------------------------------------
// Fused GEMM + epilogue. Grid (8 m, 32 n-pairs), block 512 (8 waves).
// Tile: 128 b x 64 n (2 trees), full K = 2048 (32 kt of BK=64), double-buffered
// LDS, global_load_lds(16B) staging. Wave wv: wr=wv>>1 m-quadrant (32 rows),
// wc=wv&1 n-half (32 cols); 2x2 16x16x32 fragments.
// After the K-loop: C -> LDS (Cl[128][65] f32, aliased over As/Bs), then
// per-(b, tree) softmax/gate epilogue in-block; tree pair combined via LDS;
// write ptl2[by][27][b].
// ---------------------------------------------------------------------------
__global__ __launch_bounds__(512) void fused_kernel(
    const unsigned short* __restrict__ A,    // db [1024][2048]
    const unsigned short* __restrict__ Bm,   // Wf [2048][2048]
    const float* __restrict__ b_clc, const float* __restrict__ b1,
    const float* __restrict__ b2, const float* __restrict__ w2,
    const int* __restrict__ cc, float* __restrict__ ptl2)
{
    __shared__ __align__(16) char smem[49152];
    unsigned short (*As)[128][BK] = (unsigned short(*)[128][BK])smem;           // 2x16 KB
    unsigned short (*Bs)[64][BK]  = (unsigned short(*)[64][BK])(smem + 32768);  // 2x8 KB
    float* Cl  = (float*)smem;             // [128][65] = 33,280 B (alias)
    float* red = (float*)(smem + 34816);   // [27][128] = 13,824 B (alias)

    int tid = threadIdx.x;
    int lane = tid & 63;
    int wv = tid >> 6;          // 0..7
    int wr = wv >> 1;           // 0..3
    int wc = wv & 1;            // 0..1
    int m0 = blockIdx.x * 128;
    int n0 = blockIdx.y * 64;
    int r0 = lane & 15;
    int kq = lane >> 4;

    f32x4 acc[2][2];
#pragma unroll
    for (int mi = 0; mi < 2; ++mi)
#pragma unroll
        for (int ni = 0; ni < 2; ++ni) acc[mi][ni] = (f32x4)0.f;

#define STAGE(buf, kt)                                                          \
    {                                                                           \
        size_t koff = (size_t)(kt) * BK;                                        \
        _Pragma("unroll")                                                       \
        for (int p = 0; p < 2; ++p) {                                           \
            int chunk = p * 512 + tid;                                          \
            int row = chunk >> 3, c = chunk & 7;                                \
            const unsigned short* ga = A + (size_t)(m0 + row) * ND + koff + c*8;\
            __builtin_amdgcn_global_load_lds(                                   \
                (const __attribute__((address_space(1))) void*)ga,              \
                (__attribute__((address_space(3))) void*)&As[buf][row][c * 8],  \
                16, 0, 0);                                                      \
        }                                                                       \
        {                                                                       \
            int row = tid >> 3, c = tid & 7;                                    \
            const unsigned short* gb = Bm + (size_t)(n0 + row) * ND + koff + c*8;\
            __builtin_amdgcn_global_load_lds(                                   \
                (const __attribute__((address_space(1))) void*)gb,              \
                (__attribute__((address_space(3))) void*)&Bs[buf][row][c * 8],  \
                16, 0, 0);                                                      \
        }                                                                       \
    }

    STAGE(0, 0);
    __syncthreads();

    int cur = 0;
    for (int kt = 0; kt < 32; ++kt) {
        if (kt < 31) STAGE(cur ^ 1, kt + 1);

        short8 af[2][2], bf[2][2];   // [rep][ksub]
#pragma unroll
        for (int mi = 0; mi < 2; ++mi)
#pragma unroll
            for (int ks = 0; ks < 2; ++ks)
                af[mi][ks] = *(const short8*)&As[cur][wr*32 + mi*16 + r0][ks*32 + kq*8];
#pragma unroll
        for (int ni = 0; ni < 2; ++ni)
#pragma unroll
            for (int ks = 0; ks < 2; ++ks)
                bf[ni][ks] = *(const short8*)&Bs[cur][wc*32 + ni*16 + r0][ks*32 + kq*8];
#pragma unroll
        for (int ks = 0; ks < 2; ++ks)
#pragma unroll
            for (int mi = 0; mi < 2; ++mi)
#pragma unroll
                for (int ni = 0; ni < 2; ++ni)
                    acc[mi][ni] = __builtin_amdgcn_mfma_f32_16x16x32_bf16(
                        af[mi][ks], bf[ni][ks], acc[mi][ni], 0, 0, 0);
        __syncthreads();
        cur ^= 1;
    }
#undef STAGE

    // C -> LDS transpose. D layout (proven R4): n = wc*32+ni*16+r0,
    // b = wr*32+mi*16+kq*4+q. Cl row stride 65 -> <=2-way banks each way.
#pragma unroll
    for (int mi = 0; mi < 2; ++mi)
#pragma unroll
        for (int ni = 0; ni < 2; ++ni) {
            int n = wc * 32 + ni * 16 + r0;
            int bl = wr * 32 + mi * 16 + kq * 4;
#pragma unroll
            for (int q = 0; q < 4; ++q)
                Cl[(bl + q) * 65 + n] = acc[mi][ni][q];
        }
    __syncthreads();

    // ---- epilogue: 256 threads = 128 b x 2 trees ----
    float s[NP];
    int tl = tid >> 7;          // tree within pair (for tid < 256)
    int bl = tid & 127;
    if (tid < 256) {
        int t = blockIdx.y * 2 + tl;

        float a21[21];
#pragma unroll
        for (int k = 0; k < 21; ++k) a21[k] = Cl[bl * 65 + tl * 32 + k];

        float L0 = a21[0] + b_clc[t * 2 + 0];
        float L1 = a21[1] + b_clc[t * 2 + 1];
        float mm = fmaxf(L0, L1);
        float e0 = __expf(L0 - mm), e1 = __expf(L1 - mm);
        float gate = e1 / (e0 + e1);

        float l1v[3];
        float m1 = -3.0e38f;
#pragma unroll
        for (int c = 0; c < 3; ++c) {
            l1v[c] = a21[2 + c] + b1[t * 3 + c];
            m1 = fmaxf(m1, l1v[c]);
        }
        float p1[3]; float S1 = 0.f;
#pragma unroll
        for (int c = 0; c < 3; ++c) { p1[c] = __expf(l1v[c] - m1); S1 += p1[c]; }
        float invS1g = gate / S1;

        float r0f = fmaxf(l1v[0], 0.f);
        float r1f = fmaxf(l1v[1], 0.f);
        float r2f = fmaxf(l1v[2], 0.f);

        const float* w2t = w2 + ((size_t)t * NW2ROW + NF) * 16;
        float l2[16]; float m2 = -3.0e38f;
#pragma unroll
        for (int nn = 0; nn < 16; ++nn) {
            float v = a21[5 + nn] + b2[t * 16 + nn];
            v = fmaf(r0f, w2t[nn], v);
            v = fmaf(r1f, w2t[16 + nn], v);
            v = fmaf(r2f, w2t[32 + nn], v);
            l2[nn] = v;
            m2 = fmaxf(m2, v);
        }
        float S2 = 0.f; float p2[16];
#pragma unroll
        for (int nn = 0; nn < 16; ++nn) { p2[nn] = __expf(l2[nn] - m2); S2 += p2[nn]; }
        float invS2g = gate * __frcp_rn(S2);

#pragma unroll
        for (int k = 0; k < NP; ++k) s[k] = 0.f;
#pragma unroll
        for (int c = 0; c < 3; ++c) {
            int sl = cc[t * 3 + c];
            float pc = p1[c] * invS1g;
#pragma unroll
            for (int x = 0; x < 5; ++x) {
                if (sl == x) { s[x] += pc; s[5 + x] += gate; }
            }
        }
#pragma unroll
        for (int nn = 0; nn < 16; ++nn) s[10 + nn] += p2[nn] * invS2g;
        s[26] += gate;

        if (tl == 1) {
#pragma unroll
            for (int k = 0; k < NP; ++k) red[k * 128 + bl] = s[k];
        }
    }
    __syncthreads();

    if (tid < 128) {
        float* pt = ptl2 + (size_t)blockIdx.y * NP * NB + m0 + bl;
#pragma unroll
        for (int k = 0; k < NP; ++k)
            pt[(size_t)k * NB] = s[k] + red[k * 128 + bl];
    }
}

// ---------------------------------------------------------------------------
// Finalize: reduce 32 tree-pair slices (fixed order), normalize, write
// out[b][21]. Grid 16, block 256 (4 waves; wave w owns slices w, w+4, ...).
// ---------------------------------------------------------------------------
__global__ __launch_bounds__(256) void finalize_kernel(
    const float* __restrict__ ptl2, float* __restrict__ out)
{
    int lane = threadIdx.x & 63;
    int w = threadIdx.x >> 6;           // 0..3
    int b = blockIdx.x * 64 + lane;

    float s[NP];
#pragma unroll
    for (int k = 0; k < NP; ++k) s[k] = 0.f;
#pragma unroll
    for (int i = 0; i < 8; ++i) {
        const float* pt = ptl2 + (size_t)(w + i * 4) * NP * NB + b;
#pragma unroll
        for (int k = 0; k < NP; ++k) s[k] += pt[(size_t)k * NB];
    }

    __shared__ float red[3][NP][64];
    if (w > 0) {
#pragma unroll
        for (int k = 0; k < NP; ++k) red[w - 1][k][lane] = s[k];
    }
    __syncthreads();
    if (w != 0) return;
#pragma unroll
    for (int r = 0; r < 3; ++r)
#pragma unroll
        for (int k = 0; k < NP; ++k) s[k] += red[r][k][lane];

    float* ob = out + (size_t)b * 21;
#pragma unroll
    for (int x = 0; x < 5; ++x) {
        float c = s[5 + x];
        ob[x] = (c > 0.f) ? (s[x] / c) : 0.f;
    }
    float invg = 1.f / s[26];
#pragma unroll
    for (int n = 0; n < 16; ++n) ob[5 + n] = s[10 + n] * invg;
}

// ---------------------------------------------------------------------------
extern "C" void kernel_launch(void* const* d_in, const int* in_sizes, int n_in,
                              void* d_out, int out_size, void* d_ws, size_t ws_size,
                              hipStream_t stream)
{
    const float* d     = (const float*)d_in[0];
    const int*   idx   = (const int*)  d_in[1];
    const int*   cc    = (const int*)  d_in[2];
    const float* w_clc = (const float*)d_in[3];
    const float* b_clc = (const float*)d_in[4];
    const float* w1    = (const float*)d_in[5];
    const float* b1    = (const float*)d_in[6];
    const float* w2    = (const float*)d_in[7];
    const float* b2    = (const float*)d_in[8];
    float* out = (float*)d_out;

    // ws layout
    unsigned short* Wf = (unsigned short*)d_ws;            // [2048][2048] bf16 = 8 MB
    unsigned short* db = Wf + (size_t)NN2 * ND;            // [1024][2048] bf16 = 4 MB
    float* ptl2 = (float*)(db + (size_t)NB * ND);          // [32][27][1024] f32

    prep_kernel<<<NSCAT + NCONV, 256, 0, stream>>>(idx, w_clc, w1, w2, d, Wf, db);
    fused_kernel<<<dim3(8, 32), 512, 0, stream>>>(db, Wf, b_clc, b1, b2, w2, cc, ptl2);
    finalize_kernel<<<16, 256, 0, stream>>>(ptl2, out);
}